// Round 1
// baseline (406.016 us; speedup 1.0000x reference)
//
#include <hip/hip_runtime.h>

typedef unsigned short u16;
typedef unsigned int u32;
typedef __bf16 bf16x8 __attribute__((ext_vector_type(8)));
typedef float f32x4 __attribute__((ext_vector_type(4)));
typedef u16 u16x4 __attribute__((ext_vector_type(4)));
typedef u16 u16x8 __attribute__((ext_vector_type(8)));

__device__ __forceinline__ float b2f(u16 u) {
  union { float f; u32 i; } x; x.i = ((u32)u) << 16; return x.f;
}
__device__ __forceinline__ u16 f2b(float f) {
  union { float f; u32 i; } x; x.f = f;
  u32 r = (x.i + 0x7fffu + ((x.i >> 16) & 1u)) >> 16;
  return (u16)r;
}

__device__ __forceinline__ void gload16(const void* g, void* l) {
  __builtin_amdgcn_global_load_lds(
      (const __attribute__((address_space(1))) void*)g,
      (__attribute__((address_space(3))) void*)l, 16, 0, 0);
}

// ---------------- converts ----------------

// inputs [8192][2048] f32 -> visB [8192][1024] bf16, textB [8192][1024] bf16
__global__ void convert_split(const float* __restrict__ in,
                              u16* __restrict__ vis, u16* __restrict__ txt) {
  size_t i = ((size_t)blockIdx.x * 256 + threadIdx.x) * 4;
  f32x4 v = *reinterpret_cast<const f32x4*>(in + i);
  size_t row = i >> 11;
  int col = (int)(i & 2047);
  u16x4 o = { f2b(v[0]), f2b(v[1]), f2b(v[2]), f2b(v[3]) };
  u16* dst = (col < 1024) ? (vis + row * 1024 + col)
                          : (txt + row * 1024 + (col - 1024));
  *reinterpret_cast<u16x4*>(dst) = o;
}

// plain f32 -> bf16 (weights), n = gridDim.x*256*4 elements exactly
__global__ void convert_bf16(const float* __restrict__ in, u16* __restrict__ out) {
  size_t i = ((size_t)blockIdx.x * 256 + threadIdx.x) * 4;
  f32x4 v = *reinterpret_cast<const f32x4*>(in + i);
  u16x4 o = { f2b(v[0]), f2b(v[1]), f2b(v[2]), f2b(v[3]) };
  *reinterpret_cast<u16x4*>(out + i) = o;
}

// vision slice of inputs (f32, row stride 2048) -> visT [b][1024][2048] bf16
__global__ void transpose_vision(const float* __restrict__ in, u16* __restrict__ out) {
  __shared__ float tile[64][65];
  const float* src = in + (size_t)blockIdx.z * (2048u * 2048u);
  u16* dst = out + (size_t)blockIdx.z * (1024u * 2048u);
  const int t = threadIdx.x;
  const int s0 = blockIdx.y * 64, d0 = blockIdx.x * 64;
#pragma unroll
  for (int p = 0; p < 16; ++p) {
    int idx = p * 256 + t; int r = idx >> 6, c = idx & 63;
    tile[r][c] = src[(size_t)(s0 + r) * 2048 + d0 + c];
  }
  __syncthreads();
#pragma unroll
  for (int p = 0; p < 16; ++p) {
    int idx = p * 256 + t; int r = idx >> 6, c = idx & 63;
    dst[(size_t)(d0 + r) * 2048 + s0 + c] = f2b(tile[c][r]);
  }
}

// bf16 [b][rows][cols] -> [b][cols][rows]
__global__ void transpose_bf16(const u16* __restrict__ in, u16* __restrict__ out,
                               int rows, int cols, long inB, long outB) {
  __shared__ u16 tile[64][65];
  const u16* src = in + (size_t)blockIdx.z * inB;
  u16* dst = out + (size_t)blockIdx.z * outB;
  const int t = threadIdx.x;
  const int r0 = blockIdx.y * 64, c0 = blockIdx.x * 64;
#pragma unroll
  for (int p = 0; p < 16; ++p) {
    int idx = p * 256 + t; int r = idx >> 6, c = idx & 63;
    tile[r][c] = src[(size_t)(r0 + r) * cols + c0 + c];
  }
  __syncthreads();
#pragma unroll
  for (int p = 0; p < 16; ++p) {
    int idx = p * 256 + t; int r = idx >> 6, c = idx & 63;
    dst[(size_t)(c0 + r) * rows + r0 + c] = tile[c][r];
  }
}

// ---------------- softmax (rows of 2048, in-place, bf16) ----------------
__launch_bounds__(256)
__global__ void softmax_kernel(u16* __restrict__ S) {
  __shared__ float red[8];
  u16* p = S + (size_t)blockIdx.x * 2048;
  const int t = threadIdx.x;
  u16x8 u = *reinterpret_cast<const u16x8*>(p + t * 8);
  float v[8];
#pragma unroll
  for (int j = 0; j < 8; ++j) v[j] = b2f(u[j]);
  float mx = v[0];
#pragma unroll
  for (int j = 1; j < 8; ++j) mx = fmaxf(mx, v[j]);
#pragma unroll
  for (int off = 32; off; off >>= 1) mx = fmaxf(mx, __shfl_xor(mx, off));
  if ((t & 63) == 0) red[t >> 6] = mx;
  __syncthreads();
  mx = fmaxf(fmaxf(red[0], red[1]), fmaxf(red[2], red[3]));
  float e[8], s = 0.f;
#pragma unroll
  for (int j = 0; j < 8; ++j) { e[j] = __expf(v[j] - mx); s += e[j]; }
#pragma unroll
  for (int off = 32; off; off >>= 1) s += __shfl_xor(s, off);
  if ((t & 63) == 0) red[4 + (t >> 6)] = s;
  __syncthreads();
  s = red[4] + red[5] + red[6] + red[7];
  const float inv = 1.0f / s;
  u16x8 o;
#pragma unroll
  for (int j = 0; j < 8; ++j) o[j] = f2b(e[j] * inv);
  *reinterpret_cast<u16x8*>(p + t * 8) = o;
}

// ---------------- NT GEMM: C[m][n] = scale * sum_k A[m][k]*B[n][k] (+bias[n]) ----------------
// 128x128 tile, 4 waves (2x2), 4x4 fragments of 16x16x32 bf16 MFMA.
// MODE 0: bf16 output; MODE 2: f32 output.
template<int MODE>
__launch_bounds__(256)
__global__ void gemm_nt(const u16* __restrict__ A, const u16* __restrict__ B,
                        const float* __restrict__ bias, void* __restrict__ Cout,
                        int K, int lda, int ldb, int ldc,
                        long sA, long sB, long sC, float scale) {
  __shared__ u16 lds[2][2][128 * 32];
  const int t = threadIdx.x;
  const size_t z = blockIdx.z;
  A += z * (size_t)sA;
  B += z * (size_t)sB;
  const int bm = blockIdx.y, bn = blockIdx.x;
  const int lane = t & 63;
  const int wave = t >> 6;
  const int wr = (wave >> 1) << 6, wc = (wave & 1) << 6;
  const int fr = lane & 15, kh = lane >> 4;

  const int rA = bm * 128 + (t >> 2);
  const int rB = bn * 128 + (t >> 2);
  const int ck = (t & 3) << 3;

  f32x4 acc[4][4];
  const f32x4 zero = {0.f, 0.f, 0.f, 0.f};
#pragma unroll
  for (int i = 0; i < 4; ++i)
#pragma unroll
    for (int j = 0; j < 4; ++j) acc[i][j] = zero;

  const int nk = K >> 5;

  auto STAGE = [&](int b, int k0) {
#pragma unroll
    for (int p = 0; p < 2; ++p) {
      gload16(A + (size_t)(rA + (p << 6)) * lda + k0 + ck,
              (char*)&lds[b][0][0] + t * 16 + p * 4096);
      gload16(B + (size_t)(rB + (p << 6)) * ldb + k0 + ck,
              (char*)&lds[b][1][0] + t * 16 + p * 4096);
    }
  };

  STAGE(0, 0);
  __syncthreads();
  int cur = 0;
  for (int kt = 0; kt < nk; ++kt) {
    if (kt + 1 < nk) STAGE(cur ^ 1, (kt + 1) << 5);
    bf16x8 af[4], bg[4];
    const u16* la = &lds[cur][0][0];
    const u16* lb = &lds[cur][1][0];
#pragma unroll
    for (int i = 0; i < 4; ++i)
      af[i] = *reinterpret_cast<const bf16x8*>(la + (wr + i * 16 + fr) * 32 + kh * 8);
#pragma unroll
    for (int j = 0; j < 4; ++j)
      bg[j] = *reinterpret_cast<const bf16x8*>(lb + (wc + j * 16 + fr) * 32 + kh * 8);
#pragma unroll
    for (int i = 0; i < 4; ++i)
#pragma unroll
      for (int j = 0; j < 4; ++j)
        acc[i][j] = __builtin_amdgcn_mfma_f32_16x16x32_bf16(af[i], bg[j], acc[i][j], 0, 0, 0);
    __syncthreads();
    cur ^= 1;
  }

  const int m0 = bm * 128 + wr + kh * 4;
  const int n0 = bn * 128 + wc + fr;
#pragma unroll
  for (int i = 0; i < 4; ++i) {
#pragma unroll
    for (int j = 0; j < 4; ++j) {
      const int n = n0 + j * 16;
      const float bb = (MODE == 0 && bias) ? bias[n] : 0.f;
#pragma unroll
      for (int r = 0; r < 4; ++r) {
        const int m = m0 + i * 16 + r;
        float v = acc[i][j][r] * scale + bb;
        if (MODE == 0)
          ((u16*)Cout)[z * (size_t)sC + (size_t)m * ldc + n] = f2b(v);
        else
          ((float*)Cout)[z * (size_t)sC + (size_t)m * ldc + n] = v;
      }
    }
  }
}

// ---------------- launch ----------------
extern "C" void kernel_launch(void* const* d_in, const int* in_sizes, int n_in,
                              void* d_out, int out_size, void* d_ws, size_t ws_size,
                              hipStream_t stream) {
  const float* inp = (const float*)d_in[0];
  const float* Wq  = (const float*)d_in[1];
  const float* bq  = (const float*)d_in[2];
  const float* Wk  = (const float*)d_in[3];
  const float* bk  = (const float*)d_in[4];
  const float* Wv  = (const float*)d_in[5];
  const float* bv  = (const float*)d_in[6];
  float* out = (float*)d_out;
  char* ws = (char*)d_ws;

  // workspace layout (bytes); total 106,954,752
  u16* visB  = (u16*)(ws + 0);         // [8192][1024] bf16 (dead after Q proj)
  u16* textB = (u16*)(ws + 16777216);  // [8192][1024] bf16 (dead after K/V proj)
  u16* Vtmp  = (u16*)(ws + 0);         // aliases visB: V [8192][1024] (dead after V transpose)
  u16* Sattn = (u16*)(ws + 0);         // aliases visB+textB: [4][2048][2048] bf16 scores->attn
  u16* visT  = (u16*)(ws + 33554432);  // [4][1024][2048] bf16
  u16* WqB   = (u16*)(ws + 50331648);
  u16* WkB   = (u16*)(ws + 52428800);
  u16* WvB   = (u16*)(ws + 54525952);
  u16* Qb    = (u16*)(ws + 56623104);  // [4][2048][1024] (dead after scores)
  u16* Kb    = (u16*)(ws + 73400320);  // [4][2048][1024] (dead after scores)
  u16* attnT = (u16*)(ws + 56623104);  // aliases Qb+Kb: [4][2048][2048] bf16
  u16* Vt    = (u16*)(ws + 90177536);  // [4][1024][2048] bf16

  convert_split<<<16384, 256, 0, stream>>>(inp, visB, textB);
  convert_bf16<<<1024, 256, 0, stream>>>(Wq, WqB);
  convert_bf16<<<1024, 256, 0, stream>>>(Wk, WkB);
  convert_bf16<<<1024, 256, 0, stream>>>(Wv, WvB);
  transpose_vision<<<dim3(16, 32, 4), 256, 0, stream>>>(inp, visT);

  // Q = visB @ WqB^T + bq ; K = textB @ WkB^T + bk ; V = textB @ WvB^T + bv
  gemm_nt<0><<<dim3(8, 64, 1), 256, 0, stream>>>(visB,  WqB, bq, Qb,   1024, 1024, 1024, 1024, 0, 0, 0, 1.f);
  gemm_nt<0><<<dim3(8, 64, 1), 256, 0, stream>>>(textB, WkB, bk, Kb,   1024, 1024, 1024, 1024, 0, 0, 0, 1.f);
  gemm_nt<0><<<dim3(8, 64, 1), 256, 0, stream>>>(textB, WvB, bv, Vtmp, 1024, 1024, 1024, 1024, 0, 0, 0, 1.f);

  // Vt[b][d][k] = V[b][k][d]
  transpose_bf16<<<dim3(16, 32, 4), 256, 0, stream>>>(Vtmp, Vt, 2048, 1024, 2048L * 1024, 1024L * 2048);

  // scores[b][q][k] = (Q.K^T)/32, bf16 into Sattn (clobbers visB/textB/Vtmp — all dead)
  gemm_nt<0><<<dim3(16, 16, 4), 256, 0, stream>>>(Qb, Kb, nullptr, Sattn, 1024, 1024, 1024, 2048,
                                                  2097152, 2097152, 4194304, 0.03125f);
  softmax_kernel<<<8192, 256, 0, stream>>>(Sattn);

  // attnT[b][k][q] (clobbers Qb/Kb — dead)
  transpose_bf16<<<dim3(32, 32, 4), 256, 0, stream>>>(Sattn, attnT, 2048, 2048, 4194304L, 4194304L);

  // cav[b][q][d] = sum_k attn[q][k] * Vt[d][k]
  gemm_nt<2><<<dim3(8, 16, 4), 256, 0, stream>>>(Sattn, Vt, nullptr, out, 2048, 2048, 2048, 1024,
                                                 4194304, 2097152, 2097152, 1.f);
  // cat[b][k][d] = sum_q attnT[k][q] * visT[d][q]
  gemm_nt<2><<<dim3(8, 16, 4), 256, 0, stream>>>(attnT, visT, nullptr, out + 8388608, 2048, 2048, 2048, 1024,
                                                 4194304, 2097152, 2097152, 1.f);
}

// Round 2
// 338.129 us; speedup vs baseline: 1.2008x; 1.2008x over previous
//
#include <hip/hip_runtime.h>

typedef unsigned short u16;
typedef unsigned int u32;
typedef __bf16 bf16x8 __attribute__((ext_vector_type(8)));
typedef float f32x4 __attribute__((ext_vector_type(4)));
typedef u16 u16x4 __attribute__((ext_vector_type(4)));
typedef u16 u16x8 __attribute__((ext_vector_type(8)));

__device__ __forceinline__ float b2f(u16 u) {
  union { float f; u32 i; } x; x.i = ((u32)u) << 16; return x.f;
}
__device__ __forceinline__ u16 f2b(float f) {
  union { float f; u32 i; } x; x.f = f;
  u32 r = (x.i + 0x7fffu + ((x.i >> 16) & 1u)) >> 16;
  return (u16)r;
}

__device__ __forceinline__ void gload16(const void* g, void* l) {
  __builtin_amdgcn_global_load_lds(
      (const __attribute__((address_space(1))) void*)g,
      (__attribute__((address_space(3))) void*)l, 16, 0, 0);
}

// ---------------- converts ----------------

__global__ void convert_split(const float* __restrict__ in,
                              u16* __restrict__ vis, u16* __restrict__ txt) {
  size_t i = ((size_t)blockIdx.x * 256 + threadIdx.x) * 4;
  f32x4 v = *reinterpret_cast<const f32x4*>(in + i);
  size_t row = i >> 11;
  int col = (int)(i & 2047);
  u16x4 o = { f2b(v[0]), f2b(v[1]), f2b(v[2]), f2b(v[3]) };
  u16* dst = (col < 1024) ? (vis + row * 1024 + col)
                          : (txt + row * 1024 + (col - 1024));
  *reinterpret_cast<u16x4*>(dst) = o;
}

__global__ void convert_bf16(const float* __restrict__ in, u16* __restrict__ out) {
  size_t i = ((size_t)blockIdx.x * 256 + threadIdx.x) * 4;
  f32x4 v = *reinterpret_cast<const f32x4*>(in + i);
  u16x4 o = { f2b(v[0]), f2b(v[1]), f2b(v[2]), f2b(v[3]) };
  *reinterpret_cast<u16x4*>(out + i) = o;
}

// vision slice of inputs (f32, row stride 2048) -> visT [b][1024][2048] bf16
__global__ void transpose_vision(const float* __restrict__ in, u16* __restrict__ out) {
  __shared__ float tile[64][65];
  const float* src = in + (size_t)blockIdx.z * (2048u * 2048u);
  u16* dst = out + (size_t)blockIdx.z * (1024u * 2048u);
  const int t = threadIdx.x;
  const int s0 = blockIdx.y * 64, d0 = blockIdx.x * 64;
#pragma unroll
  for (int p = 0; p < 16; ++p) {
    int idx = p * 256 + t; int r = idx >> 6, c = idx & 63;
    tile[r][c] = src[(size_t)(s0 + r) * 2048 + d0 + c];
  }
  __syncthreads();
#pragma unroll
  for (int p = 0; p < 16; ++p) {
    int idx = p * 256 + t; int r = idx >> 6, c = idx & 63;
    dst[(size_t)(d0 + r) * 2048 + s0 + c] = f2b(tile[c][r]);
  }
}

// bf16 [b][rows][cols] -> [b][cols][rows]
__global__ void transpose_bf16(const u16* __restrict__ in, u16* __restrict__ out,
                               int rows, int cols, long inB, long outB) {
  __shared__ u16 tile[64][65];
  const u16* src = in + (size_t)blockIdx.z * inB;
  u16* dst = out + (size_t)blockIdx.z * outB;
  const int t = threadIdx.x;
  const int r0 = blockIdx.y * 64, c0 = blockIdx.x * 64;
#pragma unroll
  for (int p = 0; p < 16; ++p) {
    int idx = p * 256 + t; int r = idx >> 6, c = idx & 63;
    tile[r][c] = src[(size_t)(r0 + r) * cols + c0 + c];
  }
  __syncthreads();
#pragma unroll
  for (int p = 0; p < 16; ++p) {
    int idx = p * 256 + t; int r = idx >> 6, c = idx & 63;
    dst[(size_t)(c0 + r) * rows + r0 + c] = tile[c][r];
  }
}

// ---------------- softmax (rows of 2048, in-place, bf16) ----------------
__launch_bounds__(256)
__global__ void softmax_kernel(u16* __restrict__ S) {
  __shared__ float red[8];
  u16* p = S + (size_t)blockIdx.x * 2048;
  const int t = threadIdx.x;
  u16x8 u = *reinterpret_cast<const u16x8*>(p + t * 8);
  float v[8];
#pragma unroll
  for (int j = 0; j < 8; ++j) v[j] = b2f(u[j]);
  float mx = v[0];
#pragma unroll
  for (int j = 1; j < 8; ++j) mx = fmaxf(mx, v[j]);
#pragma unroll
  for (int off = 32; off; off >>= 1) mx = fmaxf(mx, __shfl_xor(mx, off));
  if ((t & 63) == 0) red[t >> 6] = mx;
  __syncthreads();
  mx = fmaxf(fmaxf(red[0], red[1]), fmaxf(red[2], red[3]));
  float e[8], s = 0.f;
#pragma unroll
  for (int j = 0; j < 8; ++j) { e[j] = __expf(v[j] - mx); s += e[j]; }
#pragma unroll
  for (int off = 32; off; off >>= 1) s += __shfl_xor(s, off);
  if ((t & 63) == 0) red[4 + (t >> 6)] = s;
  __syncthreads();
  s = red[4] + red[5] + red[6] + red[7];
  const float inv = 1.0f / s;
  u16x8 o;
#pragma unroll
  for (int j = 0; j < 8; ++j) o[j] = f2b(e[j] * inv);
  *reinterpret_cast<u16x8*>(p + t * 8) = o;
}

// ============ 256x256 8-phase NT GEMM (T2 swizzle + T3/T4 counted vmcnt + T5) ============
// C[m][n] = scale * sum_k A[m][k]*B[n][k] (+bias[n]); per-z pointer tables.
// 8 waves (2M x 4N), wave tile 128x64, BK=64 (2 k-steps of 16x16x32 MFMA).
// LDS 128KB: buf{0,1} x { A0(16K) A1(16K) B0(16K) B1(16K) }, rows of 128B,
// XOR-swizzled: phys_byte = row*128 + (colbyte ^ ((row&7)<<4)).

struct GArgs {
  const u16* A[8]; const u16* B[8]; const float* bias[8]; void* C[8];
  int K, lda, ldb, ldc; float scale; int obf16;
};

#define FENCE() asm volatile("" ::: "memory")
#define BARF()  { FENCE(); __builtin_amdgcn_s_barrier(); FENCE(); }
#define LGKM0() { asm volatile("s_waitcnt lgkmcnt(0)" ::: "memory"); __builtin_amdgcn_sched_barrier(0); }
#define LGKM8() asm volatile("s_waitcnt lgkmcnt(8)" ::: "memory")
#define VMC4()  asm volatile("s_waitcnt vmcnt(4)" ::: "memory")
#define PRIO1() __builtin_amdgcn_s_setprio(1)
#define PRIO0() { __builtin_amdgcn_s_setprio(0); __builtin_amdgcn_sched_barrier(0); }

__launch_bounds__(512, 2)
__global__ void gemm256(GArgs args) {
  __shared__ u16 lds[65536];  // 128 KiB
  char* L = (char*)lds;
  const int t = threadIdx.x;
  const int z = blockIdx.z;
  const u16* A  = args.A[z];
  const u16* Bm = args.B[z];
  const int K = args.K, lda = args.lda, ldb = args.ldb, ldc = args.ldc;
  const int bm = blockIdx.y, bn = blockIdx.x;
  const int lane = t & 63, wave = t >> 6;
  const int wr = (wave >> 2) * 128;   // 0 / 128
  const int wc = (wave & 3) * 64;     // 0,64,128,192
  const int fr = lane & 15, kh = lane >> 4;
  const int sw = (fr & 7) << 4;
  // ds_read column-phys offsets for kk=0/1 (bits 4-6 xor'd with sw)
  const u32 cK0 = (u32)((kh << 4) ^ sw);
  const u32 cK1 = (u32)((64 | (kh << 4)) ^ sw);
  const u32 offA = (u32)((wr ? 16384 : 0) + fr * 128);
  const u32 offB = (u32)(32768 + ((wc & 128) ? 16384 : 0) + ((wc & 64) ? 8192 : 0) + fr * 128);
  // staging thread constants (inverse-swizzled source)
  const int srow = t >> 3;  // 0..63
  const int scol = ((((t & 7) << 4) ^ (((t >> 3) & 7) << 4)) >> 1);  // elems
  const u32 sdst = (u32)(t * 16);
  const u16* Ab = A  + (size_t)(bm * 256 + srow) * lda + scol;
  const u16* Bb = Bm + (size_t)(bn * 256 + srow) * ldb + scol;

  f32x4 acc[8][4];
  const f32x4 zero = {0.f, 0.f, 0.f, 0.f};
#pragma unroll
  for (int a = 0; a < 8; ++a)
#pragma unroll
    for (int n = 0; n < 4; ++n) acc[a][n] = zero;

  bf16x8 af[4][2], bg0[2][2], bg1[2][2];

  auto STAGE_A = [&](int bufOff, int half, int k0) {
    const u16* s = Ab + (size_t)(half * 128) * lda + k0;
    char* d = L + bufOff + half * 16384 + sdst;
    gload16(s, d);
    gload16(s + (size_t)64 * lda, d + 8192);
  };
  auto STAGE_B = [&](int bufOff, int half, int k0) {
    const u16* s = Bb + (size_t)(half * 128) * ldb + k0;
    char* d = L + bufOff + 32768 + half * 16384 + sdst;
    gload16(s, d);
    gload16(s + (size_t)64 * ldb, d + 8192);
  };
  auto LDA = [&](int bufOff, int h) {
#pragma unroll
    for (int mi = 0; mi < 4; ++mi) {
      u32 base = (u32)bufOff + offA + (u32)(h * 8192 + mi * 2048);
      af[mi][0] = *reinterpret_cast<const bf16x8*>(L + base + cK0);
      af[mi][1] = *reinterpret_cast<const bf16x8*>(L + base + cK1);
    }
  };
  auto LDB = [&](int bufOff, int g, bf16x8 (&bg)[2][2]) {
#pragma unroll
    for (int ni = 0; ni < 2; ++ni) {
      u32 base = (u32)bufOff + offB + (u32)(g * 4096 + ni * 2048);
      bg[ni][0] = *reinterpret_cast<const bf16x8*>(L + base + cK0);
      bg[ni][1] = *reinterpret_cast<const bf16x8*>(L + base + cK1);
    }
  };
  auto MF = [&](int h, int g, bf16x8 (&bg)[2][2]) {
#pragma unroll
    for (int mi = 0; mi < 4; ++mi)
#pragma unroll
      for (int ni = 0; ni < 2; ++ni)
#pragma unroll
        for (int kk = 0; kk < 2; ++kk)
          acc[h * 4 + mi][g * 2 + ni] = __builtin_amdgcn_mfma_f32_16x16x32_bf16(
              af[mi][kk], bg[ni][kk], acc[h * 4 + mi][g * 2 + ni], 0, 0, 0);
  };

  // ---- prologue: t0 full into buf0, t1.B0/B1 into buf1 (12 loads/thread) ----
  STAGE_A(0, 0, 0); STAGE_A(0, 1, 0); STAGE_B(0, 0, 0); STAGE_B(0, 1, 0);
  STAGE_B(65536, 0, 64); STAGE_B(65536, 1, 64);
  VMC4();
  BARF();

  const int nIter = K >> 7;  // 2 K-tiles (of 64) per iteration
  for (int it = 0; it < nIter; ++it) {
    const int tt = it * 2;
    const int k1 = (tt + 1) << 6;
    int k2 = (tt + 2) << 6; if (k2 >= K) k2 = 0;
    int k3 = (tt + 3) << 6; if (k3 >= K) k3 = 0;
    // P1: quadrant (h0,g0) of tile tt (buf0)
    LDA(0, 0); LDB(0, 0, bg0);
    STAGE_A(65536, 0, k1);
    LGKM8();
    BARF(); LGKM0();
    PRIO1(); MF(0, 0, bg0); PRIO0();
    BARF();
    // P2: (h0,g1)
    LDB(0, 1, bg1);
    STAGE_A(65536, 1, k1);
    BARF(); LGKM0();
    PRIO1(); MF(0, 1, bg1); PRIO0();
    BARF();
    // P3: (h1,g1)
    LDA(0, 1);
    STAGE_B(0, 0, k2);
    BARF(); LGKM0();
    PRIO1(); MF(1, 1, bg1); PRIO0();
    BARF();
    // P4: (h1,g0) — no new LDS reads; counted vmcnt before end barrier
    STAGE_B(0, 1, k2);
    BARF();
    PRIO1(); MF(1, 0, bg0); PRIO0();
    VMC4();
    BARF();
    // P5: tile tt+1 (buf1), (h0,g0)
    LDA(65536, 0); LDB(65536, 0, bg0);
    STAGE_A(0, 0, k2);
    LGKM8();
    BARF(); LGKM0();
    PRIO1(); MF(0, 0, bg0); PRIO0();
    BARF();
    // P6: (h0,g1)
    LDB(65536, 1, bg1);
    STAGE_A(0, 1, k2);
    BARF(); LGKM0();
    PRIO1(); MF(0, 1, bg1); PRIO0();
    BARF();
    // P7: (h1,g1)
    LDA(65536, 1);
    STAGE_B(65536, 0, k3);
    BARF(); LGKM0();
    PRIO1(); MF(1, 1, bg1); PRIO0();
    BARF();
    // P8: (h1,g0)
    STAGE_B(65536, 1, k3);
    BARF();
    PRIO1(); MF(1, 0, bg0); PRIO0();
    VMC4();
    BARF();
  }

  // ---- epilogue ----
  const float scl = args.scale;
  const float* bias = args.bias[z];
  float bv[4];
#pragma unroll
  for (int ni = 0; ni < 4; ++ni) {
    int n = bn * 256 + wc + ni * 16 + fr;
    bv[ni] = bias ? bias[n] : 0.f;
  }
  if (args.obf16) {
    u16* C = (u16*)args.C[z];
#pragma unroll
    for (int a = 0; a < 8; ++a) {
      const int mb = bm * 256 + wr + (a >> 2) * 64 + (a & 3) * 16 + kh * 4;
#pragma unroll
      for (int ni = 0; ni < 4; ++ni) {
        const int n = bn * 256 + wc + ni * 16 + fr;
#pragma unroll
        for (int r = 0; r < 4; ++r)
          C[(size_t)(mb + r) * ldc + n] = f2b(acc[a][ni][r] * scl + bv[ni]);
      }
    }
  } else {
    float* C = (float*)args.C[z];
#pragma unroll
    for (int a = 0; a < 8; ++a) {
      const int mb = bm * 256 + wr + (a >> 2) * 64 + (a & 3) * 16 + kh * 4;
#pragma unroll
      for (int ni = 0; ni < 4; ++ni) {
        const int n = bn * 256 + wc + ni * 16 + fr;
#pragma unroll
        for (int r = 0; r < 4; ++r)
          C[(size_t)(mb + r) * ldc + n] = acc[a][ni][r] * scl + bv[ni];
      }
    }
  }
}

// ---------------- launch ----------------
extern "C" void kernel_launch(void* const* d_in, const int* in_sizes, int n_in,
                              void* d_out, int out_size, void* d_ws, size_t ws_size,
                              hipStream_t stream) {
  const float* inp = (const float*)d_in[0];
  const float* Wq  = (const float*)d_in[1];
  const float* bq  = (const float*)d_in[2];
  const float* Wk  = (const float*)d_in[3];
  const float* bk  = (const float*)d_in[4];
  const float* Wv  = (const float*)d_in[5];
  const float* bv  = (const float*)d_in[6];
  float* out = (float*)d_out;
  char* ws = (char*)d_ws;

  // workspace layout (bytes); total 106,954,752
  u16* visB  = (u16*)(ws + 0);         // [8192][1024] bf16 (dead after Q proj)
  u16* textB = (u16*)(ws + 16777216);  // [8192][1024] bf16 (dead after K/V proj)
  u16* Vtmp  = (u16*)(ws + 0);         // aliases visB: V [8192][1024] (dead after V transpose)
  u16* Sattn = (u16*)(ws + 0);         // aliases visB+textB: [4][2048][2048] bf16 scores->attn
  u16* visT  = (u16*)(ws + 33554432);  // [4][1024][2048] bf16
  u16* WqB   = (u16*)(ws + 50331648);
  u16* WkB   = (u16*)(ws + 52428800);
  u16* WvB   = (u16*)(ws + 54525952);
  u16* Qb    = (u16*)(ws + 56623104);  // [4][2048][1024] (dead after scores)
  u16* Kb    = (u16*)(ws + 73400320);  // [4][2048][1024] (dead after scores)
  u16* attnT = (u16*)(ws + 56623104);  // aliases Qb+Kb: [4][2048][2048] bf16
  u16* Vt    = (u16*)(ws + 90177536);  // [4][1024][2048] bf16

  convert_split<<<16384, 256, 0, stream>>>(inp, visB, textB);
  convert_bf16<<<1024, 256, 0, stream>>>(Wq, WqB);
  convert_bf16<<<1024, 256, 0, stream>>>(Wk, WkB);
  convert_bf16<<<1024, 256, 0, stream>>>(Wv, WvB);
  transpose_vision<<<dim3(16, 32, 4), 256, 0, stream>>>(inp, visT);

  // --- projections: z=0 Q, z=1 K, z=2 V (M=8192, N=1024, K=1024) ---
  {
    GArgs g{};
    g.A[0] = visB;  g.B[0] = WqB; g.bias[0] = bq; g.C[0] = Qb;
    g.A[1] = textB; g.B[1] = WkB; g.bias[1] = bk; g.C[1] = Kb;
    g.A[2] = textB; g.B[2] = WvB; g.bias[2] = bv; g.C[2] = Vtmp;
    g.K = 1024; g.lda = 1024; g.ldb = 1024; g.ldc = 1024; g.scale = 1.f; g.obf16 = 1;
    gemm256<<<dim3(4, 32, 3), 512, 0, stream>>>(g);
  }

  // Vt[b][d][k] = V[b][k][d]
  transpose_bf16<<<dim3(16, 32, 4), 256, 0, stream>>>(Vtmp, Vt, 2048, 1024, 2048L * 1024, 1024L * 2048);

  // --- scores: z=batch (M=2048, N=2048, K=1024), clobbers visB/textB/Vtmp (dead) ---
  {
    GArgs g{};
    for (int z = 0; z < 4; ++z) {
      g.A[z] = Qb + (size_t)z * 2097152;
      g.B[z] = Kb + (size_t)z * 2097152;
      g.bias[z] = nullptr;
      g.C[z] = Sattn + (size_t)z * 4194304;
    }
    g.K = 1024; g.lda = 1024; g.ldb = 1024; g.ldc = 2048; g.scale = 0.03125f; g.obf16 = 1;
    gemm256<<<dim3(8, 8, 4), 512, 0, stream>>>(g);
  }

  softmax_kernel<<<8192, 256, 0, stream>>>(Sattn);

  // attnT[b][k][q] (clobbers Qb/Kb — dead)
  transpose_bf16<<<dim3(32, 32, 4), 256, 0, stream>>>(Sattn, attnT, 2048, 2048, 4194304L, 4194304L);

  // --- fused outputs: z<4 -> cav, z>=4 -> cat (M=2048, N=1024, K=2048) ---
  {
    GArgs g{};
    for (int z = 0; z < 4; ++z) {
      g.A[z] = Sattn + (size_t)z * 4194304;
      g.B[z] = Vt + (size_t)z * 2097152;
      g.bias[z] = nullptr;
      g.C[z] = out + (size_t)z * 2097152;
    }
    for (int z = 4; z < 8; ++z) {
      g.A[z] = attnT + (size_t)(z - 4) * 4194304;
      g.B[z] = visT + (size_t)(z - 4) * 2097152;
      g.bias[z] = nullptr;
      g.C[z] = out + 8388608 + (size_t)(z - 4) * 2097152;
    }
    g.K = 2048; g.lda = 2048; g.ldb = 2048; g.ldc = 1024; g.scale = 1.f; g.obf16 = 0;
    gemm256<<<dim3(4, 8, 8), 512, 0, stream>>>(g);
  }
}

// Round 10
// 336.900 us; speedup vs baseline: 1.2052x; 1.0036x over previous
//
#include <hip/hip_runtime.h>

typedef unsigned short u16;
typedef unsigned int u32;
typedef __bf16 bf16x8 __attribute__((ext_vector_type(8)));
typedef float f32x4 __attribute__((ext_vector_type(4)));
typedef u16 u16x4 __attribute__((ext_vector_type(4)));
typedef u16 u16x8 __attribute__((ext_vector_type(8)));

__device__ __forceinline__ float b2f(u16 u) {
  union { float f; u32 i; } x; x.i = ((u32)u) << 16; return x.f;
}
__device__ __forceinline__ u16 f2b(float f) {
  union { float f; u32 i; } x; x.f = f;
  u32 r = (x.i + 0x7fffu + ((x.i >> 16) & 1u)) >> 16;
  return (u16)r;
}

__device__ __forceinline__ void gload16(const void* g, void* l) {
  __builtin_amdgcn_global_load_lds(
      (const __attribute__((address_space(1))) void*)g,
      (__attribute__((address_space(3))) void*)l, 16, 0, 0);
}

// ---------------- fused convert: split + bf16 + vision-transpose ----------------
// inputs [8192][2048] f32 -> visB[8192][1024], textB[8192][1024], visT[4][1024][2048]
__global__ void convert_all(const float* __restrict__ in, u16* __restrict__ vis,
                            u16* __restrict__ txt, u16* __restrict__ visT) {
  __shared__ float tile[64][65];
  const int t = threadIdx.x;
  const int e0 = blockIdx.x * 64;   // 0..2047
  const int s0 = blockIdx.y * 64;   // 0..8191
  const bool isVis = e0 < 1024;
  u16* dst = isVis ? vis : txt;
  const int ec = isVis ? e0 : (e0 - 1024);
#pragma unroll
  for (int p = 0; p < 4; ++p) {
    int idx = p * 256 + t; int r = idx >> 4; int c4 = (idx & 15) << 2;
    f32x4 v = *reinterpret_cast<const f32x4*>(&in[(size_t)(s0 + r) * 2048 + e0 + c4]);
    u16x4 o = { f2b(v[0]), f2b(v[1]), f2b(v[2]), f2b(v[3]) };
    *reinterpret_cast<u16x4*>(&dst[(size_t)(s0 + r) * 1024 + ec + c4]) = o;
    if (isVis) {
      tile[r][c4] = v[0]; tile[r][c4 + 1] = v[1];
      tile[r][c4 + 2] = v[2]; tile[r][c4 + 3] = v[3];
    }
  }
  if (!isVis) return;
  __syncthreads();
  const int b = s0 >> 11, sl = s0 & 2047;
#pragma unroll
  for (int p = 0; p < 4; ++p) {
    int idx = p * 256 + t; int r = idx >> 4; int c4 = (idx & 15) << 2;
    u16x4 o = { f2b(tile[c4][r]), f2b(tile[c4 + 1][r]),
                f2b(tile[c4 + 2][r]), f2b(tile[c4 + 3][r]) };
    *reinterpret_cast<u16x4*>(
        &visT[(size_t)b * 2097152 + (size_t)(e0 + r) * 2048 + sl + c4]) = o;
  }
}

// 3 weight matrices f32->bf16 in one dispatch; grid (1024, 3)
__global__ void convert_w(const float* __restrict__ a, const float* __restrict__ b,
                          const float* __restrict__ c, u16* __restrict__ oa,
                          u16* __restrict__ ob, u16* __restrict__ oc) {
  const float* src = blockIdx.y == 0 ? a : (blockIdx.y == 1 ? b : c);
  u16* dst = blockIdx.y == 0 ? oa : (blockIdx.y == 1 ? ob : oc);
  size_t i = ((size_t)blockIdx.x * 256 + threadIdx.x) * 4;
  f32x4 v = *reinterpret_cast<const f32x4*>(src + i);
  u16x4 o = { f2b(v[0]), f2b(v[1]), f2b(v[2]), f2b(v[3]) };
  *reinterpret_cast<u16x4*>(dst + i) = o;
}

// bf16 [b][rows][cols] -> [b][cols][rows]
__global__ void transpose_bf16(const u16* __restrict__ in, u16* __restrict__ out,
                               int rows, int cols, long inB, long outB) {
  __shared__ u16 tile[64][65];
  const u16* src = in + (size_t)blockIdx.z * inB;
  u16* dst = out + (size_t)blockIdx.z * outB;
  const int t = threadIdx.x;
  const int r0 = blockIdx.y * 64, c0 = blockIdx.x * 64;
#pragma unroll
  for (int p = 0; p < 16; ++p) {
    int idx = p * 256 + t; int r = idx >> 6, c = idx & 63;
    tile[r][c] = src[(size_t)(r0 + r) * cols + c0 + c];
  }
  __syncthreads();
#pragma unroll
  for (int p = 0; p < 16; ++p) {
    int idx = p * 256 + t; int r = idx >> 6, c = idx & 63;
    dst[(size_t)(c0 + r) * rows + r0 + c] = tile[c][r];
  }
}

// ---------------- softmax (rows of 2048, in-place, bf16) ----------------
__launch_bounds__(256)
__global__ void softmax_kernel(u16* __restrict__ S) {
  __shared__ float red[8];
  u16* p = S + (size_t)blockIdx.x * 2048;
  const int t = threadIdx.x;
  u16x8 u = *reinterpret_cast<const u16x8*>(p + t * 8);
  float v[8];
#pragma unroll
  for (int j = 0; j < 8; ++j) v[j] = b2f(u[j]);
  float mx = v[0];
#pragma unroll
  for (int j = 1; j < 8; ++j) mx = fmaxf(mx, v[j]);
#pragma unroll
  for (int off = 32; off; off >>= 1) mx = fmaxf(mx, __shfl_xor(mx, off));
  if ((t & 63) == 0) red[t >> 6] = mx;
  __syncthreads();
  mx = fmaxf(fmaxf(red[0], red[1]), fmaxf(red[2], red[3]));
  float e[8], s = 0.f;
#pragma unroll
  for (int j = 0; j < 8; ++j) { e[j] = __expf(v[j] - mx); s += e[j]; }
#pragma unroll
  for (int off = 32; off; off >>= 1) s += __shfl_xor(s, off);
  if ((t & 63) == 0) red[4 + (t >> 6)] = s;
  __syncthreads();
  s = red[4] + red[5] + red[6] + red[7];
  const float inv = 1.0f / s;
  u16x8 o;
#pragma unroll
  for (int j = 0; j < 8; ++j) o[j] = f2b(e[j] * inv);
  *reinterpret_cast<u16x8*>(p + t * 8) = o;
}

// ============ 256x256 8-phase NT GEMM (T1 XCD swizzle + T2 + T3/T4 + T5) ============
struct GArgs {
  const u16* A[8]; const u16* B[8]; const float* bias[8]; void* C[8];
  int K, lda, ldb, ldc; float scale; int obf16;
};

#define FENCE() asm volatile("" ::: "memory")
#define BARF()  { FENCE(); __builtin_amdgcn_s_barrier(); FENCE(); }
#define LGKM0() { asm volatile("s_waitcnt lgkmcnt(0)" ::: "memory"); __builtin_amdgcn_sched_barrier(0); }
#define LGKM8() asm volatile("s_waitcnt lgkmcnt(8)" ::: "memory")
#define VMC4()  asm volatile("s_waitcnt vmcnt(4)" ::: "memory")
#define VMC0()  asm volatile("s_waitcnt vmcnt(0)" ::: "memory")
#define PRIO1() __builtin_amdgcn_s_setprio(1)
#define PRIO0() { __builtin_amdgcn_s_setprio(0); __builtin_amdgcn_sched_barrier(0); }

__launch_bounds__(512, 2)
__global__ void gemm256(GArgs args) {
  __shared__ u16 lds[65536];  // 128 KiB -> 1 block/CU (160KiB/CU); dispatch waves are ordered
  char* L = (char*)lds;
  const int t = threadIdx.x;

  // T1: bijective XCD-chunk remap (all grids here have total % 8 == 0)
  const int nx = gridDim.x, ny = gridDim.y;
  int bn, bm, z;
  {
    int lin = blockIdx.x + nx * (blockIdx.y + ny * blockIdx.z);
    const int tot = nx * ny * (int)gridDim.z;
    if (!(tot & 7)) {
      const int chunk = tot >> 3;
      lin = (lin & 7) * chunk + (lin >> 3);
    }
    const int nxy = nx * ny;
    z = lin / nxy;
    const int rr = lin - z * nxy;
    bm = rr / nx;
    bn = rr - bm * nx;
  }

  const u16* A  = args.A[z];
  const u16* Bm = args.B[z];
  const int K = args.K, lda = args.lda, ldb = args.ldb, ldc = args.ldc;
  const int lane = t & 63, wave = t >> 6;
  const int wr = (wave >> 2) * 128;   // 0 / 128
  const int wc = (wave & 3) * 64;     // 0,64,128,192
  const int fr = lane & 15, kh = lane >> 4;
  const int sw = (fr & 7) << 4;
  const u32 cK0 = (u32)((kh << 4) ^ sw);
  const u32 cK1 = (u32)((64 | (kh << 4)) ^ sw);
  const u32 offA = (u32)((wr ? 16384 : 0) + fr * 128);
  const u32 offB = (u32)(32768 + ((wc & 128) ? 16384 : 0) + ((wc & 64) ? 8192 : 0) + fr * 128);
  const int srow = t >> 3;
  const int scol = ((((t & 7) << 4) ^ (((t >> 3) & 7) << 4)) >> 1);
  const u32 sdst = (u32)(t * 16);
  const u16* Ab = A  + (size_t)(bm * 256 + srow) * lda + scol;
  const u16* Bb = Bm + (size_t)(bn * 256 + srow) * ldb + scol;

  f32x4 acc[8][4];
  const f32x4 zero = {0.f, 0.f, 0.f, 0.f};
#pragma unroll
  for (int a = 0; a < 8; ++a)
#pragma unroll
    for (int n = 0; n < 4; ++n) acc[a][n] = zero;

  bf16x8 af[4][2], bg0[2][2], bg1[2][2];

  auto STAGE_A = [&](int bufOff, int half, int k0) {
    const u16* s = Ab + (size_t)(half * 128) * lda + k0;
    char* d = L + bufOff + half * 16384 + sdst;
    gload16(s, d);
    gload16(s + (size_t)64 * lda, d + 8192);
  };
  auto STAGE_B = [&](int bufOff, int half, int k0) {
    const u16* s = Bb + (size_t)(half * 128) * ldb + k0;
    char* d = L + bufOff + 32768 + half * 16384 + sdst;
    gload16(s, d);
    gload16(s + (size_t)64 * ldb, d + 8192);
  };
  auto LDA = [&](int bufOff, int h) {
#pragma unroll
    for (int mi = 0; mi < 4; ++mi) {
      u32 base = (u32)bufOff + offA + (u32)(h * 8192 + mi * 2048);
      af[mi][0] = *reinterpret_cast<const bf16x8*>(L + base + cK0);
      af[mi][1] = *reinterpret_cast<const bf16x8*>(L + base + cK1);
    }
  };
  auto LDB = [&](int bufOff, int g, bf16x8 (&bg)[2][2]) {
#pragma unroll
    for (int ni = 0; ni < 2; ++ni) {
      u32 base = (u32)bufOff + offB + (u32)(g * 4096 + ni * 2048);
      bg[ni][0] = *reinterpret_cast<const bf16x8*>(L + base + cK0);
      bg[ni][1] = *reinterpret_cast<const bf16x8*>(L + base + cK1);
    }
  };
  auto MF = [&](int h, int g, bf16x8 (&bg)[2][2]) {
#pragma unroll
    for (int mi = 0; mi < 4; ++mi)
#pragma unroll
      for (int ni = 0; ni < 2; ++ni)
#pragma unroll
        for (int kk = 0; kk < 2; ++kk)
          acc[h * 4 + mi][g * 2 + ni] = __builtin_amdgcn_mfma_f32_16x16x32_bf16(
              af[mi][kk], bg[ni][kk], acc[h * 4 + mi][g * 2 + ni], 0, 0, 0);
  };

  // ---- prologue ----
  STAGE_A(0, 0, 0); STAGE_A(0, 1, 0); STAGE_B(0, 0, 0); STAGE_B(0, 1, 0);
  STAGE_B(65536, 0, 64); STAGE_B(65536, 1, 64);
  VMC4();
  BARF();

  const int nIter = K >> 7;
  for (int it = 0; it < nIter; ++it) {
    const int tt = it * 2;
    const int k1 = (tt + 1) << 6;
    int k2 = (tt + 2) << 6; if (k2 >= K) k2 = 0;
    int k3 = (tt + 3) << 6; if (k3 >= K) k3 = 0;
    // P1
    LDA(0, 0); LDB(0, 0, bg0);
    STAGE_A(65536, 0, k1);
    LGKM8();
    BARF(); LGKM0();
    PRIO1(); MF(0, 0, bg0); PRIO0();
    BARF();
    // P2
    LDB(0, 1, bg1);
    STAGE_A(65536, 1, k1);
    BARF(); LGKM0();
    PRIO1(); MF(0, 1, bg1); PRIO0();
    BARF();
    // P3
    LDA(0, 1);
    STAGE_B(0, 0, k2);
    BARF(); LGKM0();
    PRIO1(); MF(1, 1, bg1); PRIO0();
    BARF();
    // P4
    STAGE_B(0, 1, k2);
    BARF();
    PRIO1(); MF(1, 0, bg0); PRIO0();
    VMC4();
    BARF();
    // P5
    LDA(65536, 0); LDB(65536, 0, bg0);
    STAGE_A(0, 0, k2);
    LGKM8();
    BARF(); LGKM0();
    PRIO1(); MF(0, 0, bg0); PRIO0();
    BARF();
    // P6
    LDB(65536, 1, bg1);
    STAGE_A(0, 1, k2);
    BARF(); LGKM0();
    PRIO1(); MF(0, 1, bg1); PRIO0();
    BARF();
    // P7
    LDA(65536, 1);
    STAGE_B(65536, 0, k3);
    BARF(); LGKM0();
    PRIO1(); MF(1, 1, bg1); PRIO0();
    BARF();
    // P8
    STAGE_B(65536, 1, k3);
    BARF();
    PRIO1(); MF(1, 0, bg0); PRIO0();
    VMC4();
    BARF();
  }

  // ---- epilogue: drain async loads, then LDS-restage for vectorized stores ----
  VMC0();
  __syncthreads();

  const float scl = args.scale;
  const float* bias = args.bias[z];
  float bv[4];
#pragma unroll
  for (int ni = 0; ni < 4; ++ni) {
    int n = bn * 256 + wc + ni * 16 + fr;
    bv[ni] = bias ? bias[n] : 0.f;
  }
  const int wh = wave >> 2;  // slab owner (0: rows 0-127, 1: rows 128-255)

  if (args.obf16) {
    u16* C = (u16*)args.C[z];
    u16* LH = (u16*)lds;
#pragma unroll
    for (int h = 0; h < 2; ++h) {
      if (wh == h) {
#pragma unroll
        for (int a = 0; a < 8; ++a) {
          const int rb = (a >> 2) * 64 + (a & 3) * 16 + kh * 4;
#pragma unroll
          for (int ni = 0; ni < 4; ++ni) {
            const int col = wc + ni * 16 + fr;
#pragma unroll
            for (int r = 0; r < 4; ++r)
              LH[(rb + r) * 256 + col] = f2b(acc[a][ni][r] * scl + bv[ni]);
          }
        }
      }
      __syncthreads();
#pragma unroll
      for (int i = 0; i < 8; ++i) {
        int idx = i * 512 + t; int row = idx >> 5; int c8 = (idx & 31) << 3;
        *reinterpret_cast<u16x8*>(
            &C[(size_t)(bm * 256 + h * 128 + row) * ldc + bn * 256 + c8]) =
            *reinterpret_cast<const u16x8*>(&LH[row * 256 + c8]);
      }
      __syncthreads();
    }
  } else {
    float* C = (float*)args.C[z];
    float* LF = (float*)lds;
#pragma unroll
    for (int h = 0; h < 2; ++h) {
      if (wh == h) {
#pragma unroll
        for (int a = 0; a < 8; ++a) {
          const int rb = (a >> 2) * 64 + (a & 3) * 16 + kh * 4;
#pragma unroll
          for (int ni = 0; ni < 4; ++ni) {
            const int col = wc + ni * 16 + fr;
#pragma unroll
            for (int r = 0; r < 4; ++r)
              LF[(rb + r) * 256 + col] = acc[a][ni][r] * scl + bv[ni];
          }
        }
      }
      __syncthreads();
#pragma unroll
      for (int i = 0; i < 16; ++i) {
        int idx = i * 512 + t; int row = idx >> 6; int c4 = (idx & 63) << 2;
        *reinterpret_cast<f32x4*>(
            &C[(size_t)(bm * 256 + h * 128 + row) * ldc + bn * 256 + c4]) =
            *reinterpret_cast<const f32x4*>(&LF[row * 256 + c4]);
      }
      __syncthreads();
    }
  }
}

// ---------------- launch ----------------
extern "C" void kernel_launch(void* const* d_in, const int* in_sizes, int n_in,
                              void* d_out, int out_size, void* d_ws, size_t ws_size,
                              hipStream_t stream) {
  const float* inp = (const float*)d_in[0];
  const float* Wq  = (const float*)d_in[1];
  const float* bq  = (const float*)d_in[2];
  const float* Wk  = (const float*)d_in[3];
  const float* bk  = (const float*)d_in[4];
  const float* Wv  = (const float*)d_in[5];
  const float* bv  = (const float*)d_in[6];
  float* out = (float*)d_out;
  char* ws = (char*)d_ws;

  u16* visB  = (u16*)(ws + 0);
  u16* textB = (u16*)(ws + 16777216);
  u16* Vtmp  = (u16*)(ws + 0);         // aliases visB (V-proj runs in its OWN dispatch)
  u16* Sattn = (u16*)(ws + 0);         // aliases visB+textB
  u16* visT  = (u16*)(ws + 33554432);
  u16* WqB   = (u16*)(ws + 50331648);
  u16* WkB   = (u16*)(ws + 52428800);
  u16* WvB   = (u16*)(ws + 54525952);
  u16* Qb    = (u16*)(ws + 56623104);
  u16* Kb    = (u16*)(ws + 73400320);
  u16* attnT = (u16*)(ws + 56623104);  // aliases Qb+Kb
  u16* Vt    = (u16*)(ws + 90177536);

  convert_all<<<dim3(32, 128), 256, 0, stream>>>(inp, visB, textB, visT);
  convert_w<<<dim3(1024, 3), 256, 0, stream>>>(Wq, Wk, Wv, WqB, WkB, WvB);

  // projections, SPLIT to kill the visB WAR race (R8/R9 post-mortem: 1 block/CU
  // occupancy means T1 pulled V-proj blocks into the first dispatch wave,
  // racing Q's visB reads — so V must be its own stream-serialized dispatch):
  // dispatch 1: Q (reads visB) + K (reads textB) -> Qb, Kb
  {
    GArgs g{};
    g.A[0] = visB;  g.B[0] = WqB; g.bias[0] = bq; g.C[0] = Qb;
    g.A[1] = textB; g.B[1] = WkB; g.bias[1] = bk; g.C[1] = Kb;
    g.K = 1024; g.lda = 1024; g.ldb = 1024; g.ldc = 1024; g.scale = 1.f; g.obf16 = 1;
    gemm256<<<dim3(4, 32, 2), 512, 0, stream>>>(g);
  }
  // dispatch 2: V (reads textB @16-32MB) -> Vtmp (= visB @0-16MB, disjoint)
  {
    GArgs g{};
    g.A[0] = textB; g.B[0] = WvB; g.bias[0] = bv; g.C[0] = Vtmp;
    g.K = 1024; g.lda = 1024; g.ldb = 1024; g.ldc = 1024; g.scale = 1.f; g.obf16 = 1;
    gemm256<<<dim3(4, 32, 1), 512, 0, stream>>>(g);
  }

  transpose_bf16<<<dim3(16, 32, 4), 256, 0, stream>>>(Vtmp, Vt, 2048, 1024, 2048L * 1024, 1024L * 2048);

  // scores
  {
    GArgs g{};
    for (int z = 0; z < 4; ++z) {
      g.A[z] = Qb + (size_t)z * 2097152;
      g.B[z] = Kb + (size_t)z * 2097152;
      g.bias[z] = nullptr;
      g.C[z] = Sattn + (size_t)z * 4194304;
    }
    g.K = 1024; g.lda = 1024; g.ldb = 1024; g.ldc = 2048; g.scale = 0.03125f; g.obf16 = 1;
    gemm256<<<dim3(8, 8, 4), 512, 0, stream>>>(g);
  }

  softmax_kernel<<<8192, 256, 0, stream>>>(Sattn);

  transpose_bf16<<<dim3(32, 32, 4), 256, 0, stream>>>(Sattn, attnT, 2048, 2048, 4194304L, 4194304L);

  // fused outputs: z<4 cav, z>=4 cat
  {
    GArgs g{};
    for (int z = 0; z < 4; ++z) {
      g.A[z] = Sattn + (size_t)z * 4194304;
      g.B[z] = Vt + (size_t)z * 2097152;
      g.bias[z] = nullptr;
      g.C[z] = out + (size_t)z * 2097152;
    }
    for (int z = 4; z < 8; ++z) {
      g.A[z] = attnT + (size_t)(z - 4) * 4194304;
      g.B[z] = visT + (size_t)(z - 4) * 2097152;
      g.bias[z] = nullptr;
      g.C[z] = out + 8388608 + (size_t)(z - 4) * 2097152;
    }
    g.K = 2048; g.lda = 2048; g.ldb = 2048; g.ldc = 1024; g.scale = 1.f; g.obf16 = 0;
    gemm256<<<dim3(4, 8, 8), 512, 0, stream>>>(g);
  }
}